// Round 1
// baseline (1549.549 us; speedup 1.0000x reference)
//
#include <hip/hip_runtime.h>
#include <cstddef>

// Problem constants
#define NXS 64   // state dim
#define NUS 32   // input dim
#define NYS 32   // output dim
#define NWS 64   // nonlinearity dim
#define BB  256  // batch
#define TT  2048 // time steps

// Workspace layout (floats):
//  [0,     4096)  Yinv (64x64)
//  [4096, 10240)  Wz  (96x64)  z_j  = sum_k s1_k * Wz[k][j], s1=[x;u], (includes t_inv scaling)
//  [10240,16384)  Wx  (96x64)  xn_j(A-part) = sum_k s1_k * Wx[k][j]   (Y_inv folded in)
//  [16384,20480)  Wxw (64x64)  xn_j(w-part) = sum_k w_k * Wxw[k][j]   (Y_inv folded in)
//  [20480,23552)  Wy  (96x32)  y_j(A-part)
//  [23552,25600)  Wyw (64x32)  y_j(w-part)

__device__ __forceinline__ float fast_tanh(float x) {
    // tanh(x) = 1 - 2/(exp(2x)+1); graceful at +/-inf
    float e = __expf(2.0f * x);
    return 1.0f - 2.0f * __builtin_amdgcn_rcpf(e + 1.0f);
}

// ---------------------------------------------------------------------------
// Kernel 1: Gauss-Jordan inverse of Y (64x64). Y = I + 0.01*N -> strongly
// diagonally dominant, no pivoting needed. Race-free 2-region structure:
//   region A: snapshot normalized pivot row + pivot column (reads M only)
//   region B: every cell written exactly once from snapshots
__global__ __launch_bounds__(256) void invert_kernel(const float* __restrict__ Y,
                                                     float* __restrict__ ws) {
    __shared__ float M[64 * 129];   // row pad 129 -> conflict-free column walks
    __shared__ float rowk[128];
    __shared__ float ck[64];
    const int tid = threadIdx.x;

    for (int idx = tid; idx < 64 * 64; idx += 256) {
        int r = idx >> 6, c = idx & 63;
        M[r * 129 + c]      = Y[idx];
        M[r * 129 + 64 + c] = (r == c) ? 1.0f : 0.0f;
    }
    __syncthreads();

    for (int k = 0; k < 64; ++k) {
        float dv = 1.0f / M[k * 129 + k];      // uniform read, no writes in this region
        if (tid < 128) rowk[tid] = M[k * 129 + tid] * dv;
        if (tid >= 128 && tid < 192) ck[tid - 128] = M[(tid - 128) * 129 + k];
        __syncthreads();
        for (int idx = tid; idx < 64 * 128; idx += 256) {
            int r = idx >> 7, c = idx & 127;
            float cur = M[r * 129 + c];
            M[r * 129 + c] = (r == k) ? rowk[c] : cur - ck[r] * rowk[c];
        }
        __syncthreads();
    }

    for (int idx = tid; idx < 64 * 64; idx += 256) {
        int r = idx >> 6, c = idx & 63;
        ws[idx] = M[r * 129 + 64 + c];   // right half = Y^{-1}
    }
}

// ---------------------------------------------------------------------------
// Kernel 2: build fused weight matrices into ws. 21504 elements total.
__global__ __launch_bounds__(256) void prep_kernel(const float* __restrict__ lam,
                                                   const float* __restrict__ A,
                                                   const float* __restrict__ B1,
                                                   const float* __restrict__ B2,
                                                   const float* __restrict__ C1,
                                                   const float* __restrict__ D11,
                                                   const float* __restrict__ D12,
                                                   const float* __restrict__ C2,
                                                   const float* __restrict__ D21,
                                                   float* __restrict__ ws) {
    const float* __restrict__ Yinv = ws;   // written by invert_kernel
    int e = blockIdx.x * 256 + threadIdx.x;
    if (e >= 21504) return;

    if (e < 6144) {                       // Wz (96x64): C2/D21 with t_inv folded
        int k = e >> 6, j = e & 63;
        float ti = 1.0f / lam[j];
        float v = (k < 64) ? C2[j * 64 + k] : D21[j * 32 + (k - 64)];
        ws[4096 + e] = v * ti;
    } else if (e < 12288) {               // Wx (96x64): [A;B1]^T @ Yinv
        int e2 = e - 6144;
        int k = e2 >> 6, j = e2 & 63;
        float s = 0.0f;
        if (k < 64) {
            #pragma unroll 8
            for (int m = 0; m < 64; ++m) s += A[m * 64 + k] * Yinv[m * 64 + j];
        } else {
            int ku = k - 64;
            #pragma unroll 8
            for (int m = 0; m < 64; ++m) s += B1[m * 32 + ku] * Yinv[m * 64 + j];
        }
        ws[10240 + e2] = s;
    } else if (e < 16384) {               // Wxw (64x64): B2^T @ Yinv
        int e2 = e - 12288;
        int k = e2 >> 6, j = e2 & 63;
        float s = 0.0f;
        #pragma unroll 8
        for (int m = 0; m < 64; ++m) s += B2[m * 64 + k] * Yinv[m * 64 + j];
        ws[16384 + e2] = s;
    } else if (e < 19456) {               // Wy (96x32): [C1;D11]
        int e2 = e - 16384;
        int k = e2 >> 5, j = e2 & 31;
        ws[20480 + e2] = (k < 64) ? C1[j * 64 + k] : D11[j * 32 + (k - 64)];
    } else {                              // Wyw (64x32): D12
        int e2 = e - 19456;
        int k = e2 >> 5, j = e2 & 31;
        ws[23552 + e2] = D12[j * 64 + k];
    }
}

// ---------------------------------------------------------------------------
// Kernel 3: the scan. 256 blocks (1 batch chain each) x 256 threads (4 waves).
// Waves 0,1: z -> tanh -> w, then y.  Waves 2,3: x_next (x,u part before the
// barrier, w part after).  All per-lane weights permanently in VGPRs.
__global__ __launch_bounds__(256) void rnn_kernel(const float* __restrict__ xp,
                                                  const float* __restrict__ ws,
                                                  float* __restrict__ out) {
    const int b    = blockIdx.x;
    const int tid  = threadIdx.x;
    const int wave = tid >> 6;
    const int lane = tid & 63;

    __shared__ float xbuf[2][64];
    __shared__ float ubuf[2][32];
    __shared__ float wbuf[64];

    const float* __restrict__ Wz  = ws + 4096;
    const float* __restrict__ Wx  = ws + 10240;
    const float* __restrict__ Wxw = ws + 16384;
    const float* __restrict__ Wy  = ws + 20480;
    const float* __restrict__ Wyw = ws + 23552;

    const size_t ub_base = (size_t)b * (TT * NUS);   // x_pred[b]
    const size_t yb_base = (size_t)b * (TT * NYS);   // out y[b]

    if (tid < 64) xbuf[0][tid] = 0.0f;               // x0 = 0
    if (wave == 3 && lane < 32) ubuf[0][lane] = xp[ub_base + lane];
    __syncthreads();

    if (wave < 2) {
        // ---- ZY waves ----
        const int q  = wave;
        const int jz = 32 * q + (lane & 31);
        const int cz = lane >> 5;                    // K-chunk 0/1
        float wz[48];
        #pragma unroll
        for (int i = 0; i < 32; ++i) wz[i] = Wz[(32 * cz + i) * 64 + jz];
        #pragma unroll
        for (int i = 0; i < 16; ++i) wz[32 + i] = Wz[(64 + 16 * cz + i) * 64 + jz];

        const int jy = 16 * q + (lane & 15);
        const int cy = lane >> 4;                    // K-chunk 0..3
        float wyx[16], wyu[8], wywr[16];
        #pragma unroll
        for (int i = 0; i < 16; ++i) wyx[i] = Wy[(16 * cy + i) * 32 + jy];
        #pragma unroll
        for (int i = 0; i < 8; ++i)  wyu[i] = Wy[(64 + 8 * cy + i) * 32 + jy];
        #pragma unroll
        for (int i = 0; i < 16; ++i) wywr[i] = Wyw[(16 * cy + i) * 32 + jy];

        for (int t = 0; t < TT; ++t) {
            const int p = t & 1;
            const float* xb = xbuf[p];
            const float* ub = ubuf[p];

            float az = 0.0f;
            #pragma unroll
            for (int i = 0; i < 32; ++i) az += xb[32 * cz + i] * wz[i];
            #pragma unroll
            for (int i = 0; i < 16; ++i) az += ub[16 * cz + i] * wz[32 + i];
            az += __shfl_xor(az, 32);
            float wv = fast_tanh(az);
            if (cz == 0) wbuf[jz] = wv;
            __syncthreads();                         // barrier 1: w published

            float ay = 0.0f;
            #pragma unroll
            for (int i = 0; i < 16; ++i) ay += xb[16 * cy + i] * wyx[i];
            #pragma unroll
            for (int i = 0; i < 8; ++i)  ay += ub[8 * cy + i] * wyu[i];
            #pragma unroll
            for (int i = 0; i < 16; ++i) ay += wbuf[16 * cy + i] * wywr[i];
            ay += __shfl_xor(ay, 32);
            ay += __shfl_xor(ay, 16);
            if ((lane & 48) == 0) out[yb_base + (size_t)t * NYS + jy] = ay;
            __syncthreads();                         // barrier 2: step done
        }
    } else {
        // ---- XN waves ----
        const int q  = wave - 2;
        const int jx = 32 * q + (lane & 31);
        const int cx = lane >> 5;
        float wx[48];
        #pragma unroll
        for (int i = 0; i < 32; ++i) wx[i] = Wx[(32 * cx + i) * 64 + jx];
        #pragma unroll
        for (int i = 0; i < 16; ++i) wx[32 + i] = Wx[(64 + 16 * cx + i) * 64 + jx];
        float wxw[32];
        #pragma unroll
        for (int i = 0; i < 32; ++i) wxw[i] = Wxw[(32 * cx + i) * 64 + jx];

        for (int t = 0; t < TT; ++t) {
            const int p = t & 1;
            const float* xb = xbuf[p];
            const float* ub = ubuf[p];

            // prefetch u[t+1] (off critical path; consumed after barrier 1)
            float upf = 0.0f;
            if (wave == 3 && lane < 32) {
                int tn = (t + 1 < TT) ? (t + 1) : t;
                upf = xp[ub_base + (size_t)tn * NUS + lane];
            }

            float ax = 0.0f;
            #pragma unroll
            for (int i = 0; i < 32; ++i) ax += xb[32 * cx + i] * wx[i];
            #pragma unroll
            for (int i = 0; i < 16; ++i) ax += ub[16 * cx + i] * wx[32 + i];
            __syncthreads();                         // barrier 1: w available

            #pragma unroll
            for (int i = 0; i < 32; ++i) ax += wbuf[32 * cx + i] * wxw[i];
            ax += __shfl_xor(ax, 32);
            if (wave == 3 && lane < 32) ubuf[p ^ 1][lane] = upf;
            if (cx == 0) xbuf[p ^ 1][jx] = ax;
            __syncthreads();                         // barrier 2: x_next published
        }
    }

    __syncthreads();
    // x_final: last step wrote xbuf[0] (T even)
    if (tid < 64) out[(size_t)BB * TT * NYS + (size_t)b * 64 + tid] = xbuf[0][tid];
}

// ---------------------------------------------------------------------------
extern "C" void kernel_launch(void* const* d_in, const int* in_sizes, int n_in,
                              void* d_out, int out_size, void* d_ws, size_t ws_size,
                              hipStream_t stream) {
    const float* xp  = (const float*)d_in[0];
    const float* Y   = (const float*)d_in[1];
    const float* lam = (const float*)d_in[2];
    const float* A   = (const float*)d_in[3];
    const float* B1  = (const float*)d_in[4];
    const float* B2  = (const float*)d_in[5];
    const float* C1  = (const float*)d_in[6];
    const float* D11 = (const float*)d_in[7];
    const float* D12 = (const float*)d_in[8];
    const float* C2  = (const float*)d_in[9];
    const float* D21 = (const float*)d_in[10];
    float* out = (float*)d_out;
    float* ws  = (float*)d_ws;

    hipLaunchKernelGGL(invert_kernel, dim3(1),   dim3(256), 0, stream, Y, ws);
    hipLaunchKernelGGL(prep_kernel,   dim3(84),  dim3(256), 0, stream,
                       lam, A, B1, B2, C1, D11, D12, C2, D21, ws);
    hipLaunchKernelGGL(rnn_kernel,    dim3(BB),  dim3(256), 0, stream, xp, ws, out);
}